// Round 6
// baseline (46.736 us; speedup 1.0000x reference)
//
#include <hip/hip_runtime.h>

// YOLOv2 loss. preds [B,S,S,A,25] f32, labels [B,S,S,25] f32, out scalar f32.
// v6 = round-1 kernel (best measured: simple thread-per-cell, early-out,
// scalar loads) with the tiny second reduce kernel fused in via
// last-block-done counter (saves one launch + inter-kernel gap).
constexpr int kB     = 1024;
constexpr int kS     = 13;
constexpr int kA     = 5;
constexpr int kC5    = 25;
constexpr int kCells = kB * kS * kS;       // 173056
constexpr int kBlock = 256;
constexpr int kNBlk  = (kCells + kBlock - 1) / kBlock;  // 676 (exact)

__global__ __launch_bounds__(kBlock)
void yolo_fused(const float* __restrict__ preds,
                const float* __restrict__ labels,
                float* __restrict__ out,
                float* __restrict__ partial,
                unsigned* __restrict__ counter)
{
    const int tid  = threadIdx.x;
    const int lane = tid & 63;
    const int wid  = tid >> 6;
    const int cell = blockIdx.x * kBlock + tid;

    float loss = 0.0f;
    if (cell < kCells) {
        const float* lab = labels + (size_t)cell * kC5;
        if (lab[4] == 1.0f) {
            const float lx = lab[0], ly = lab[1], lw = lab[2], lh = lab[3];
            const float lx1 = lx - lw * 0.5f, lx2 = lx + lw * 0.5f;
            const float ly1 = ly - lh * 0.5f, ly2 = ly + lh * 0.5f;
            const float larea = lw * lh;

            const float* p = preds + (size_t)cell * (kA * kC5);
            float iou[kA], conf[kA];
            int best = 0;
            float bestIou = -1.0f;
            #pragma unroll
            for (int a = 0; a < kA; ++a) {
                const float* pa = p + a * kC5;
                const float px = pa[0], py = pa[1], pw = pa[2], ph = pa[3];
                conf[a] = pa[4];
                const float px1 = px - pw * 0.5f, px2 = px + pw * 0.5f;
                const float py1 = py - ph * 0.5f, py2 = py + ph * 0.5f;
                const float iw = fmaxf(fminf(px2, lx2) - fmaxf(px1, lx1), 0.0f);
                const float ih = fmaxf(fminf(py2, ly2) - fmaxf(py1, ly1), 0.0f);
                const float inter = iw * ih;
                const float uni = pw * ph + larea - inter;
                const float v = inter / (uni + 1e-12f);
                iou[a] = v;
                if (v > bestIou) { bestIou = v; best = a; }  // strict > == jnp.argmax
            }

            const float* bp = p + best * kC5;
            // xy
            const float dx = lx - bp[0], dy = ly - bp[1];
            loss += 5.0f * (dx * dx + dy * dy);
            // wh
            const float sw = sqrtf(lw) - sqrtf(bp[2]);
            const float sh = sqrtf(lh) - sqrtf(bp[3]);
            loss += sw * sw + sh * sh;
            // obj
            const float dob = bestIou - bp[4];
            loss += dob * dob;
            // cls
            float cls = 0.0f;
            #pragma unroll
            for (int c = 5; c < kC5; ++c) {
                const float d = lab[c] - bp[c];
                cls += d * d;
            }
            loss += cls;
            // noobj
            #pragma unroll
            for (int a = 0; a < kA; ++a) {
                if (a != best && iou[a] < 0.6f) {
                    const float d = iou[a] - conf[a];
                    loss += d * d;
                }
            }
        }
    }

    // block reduction
    #pragma unroll
    for (int off = 32; off > 0; off >>= 1)
        loss += __shfl_down(loss, off, 64);
    __shared__ float sred[kBlock / 64];
    __shared__ int amLast;
    if (lane == 0) sred[wid] = loss;
    __syncthreads();
    if (tid == 0) {
        const float s = sred[0] + sred[1] + sred[2] + sred[3];
        __hip_atomic_store(&partial[blockIdx.x], s, __ATOMIC_RELEASE,
                           __HIP_MEMORY_SCOPE_AGENT);
        const unsigned old = __hip_atomic_fetch_add(counter, 1u, __ATOMIC_ACQ_REL,
                                                    __HIP_MEMORY_SCOPE_AGENT);
        amLast = (old == kNBlk - 1) ? 1 : 0;
    }
    __syncthreads();

    // last block: deterministic final reduce over the 676 partials
    if (amLast) {
        float s = 0.0f;
        for (int i = tid; i < kNBlk; i += kBlock)
            s += __hip_atomic_load(&partial[i], __ATOMIC_ACQUIRE,
                                   __HIP_MEMORY_SCOPE_AGENT);
        #pragma unroll
        for (int off = 32; off > 0; off >>= 1)
            s += __shfl_down(s, off, 64);
        if (lane == 0) sred[wid] = s;
        __syncthreads();
        if (tid == 0)
            out[0] = (sred[0] + sred[1] + sred[2] + sred[3]) * (1.0f / (float)kB);
    }
}

extern "C" void kernel_launch(void* const* d_in, const int* in_sizes, int n_in,
                              void* d_out, int out_size, void* d_ws, size_t ws_size,
                              hipStream_t stream) {
    const float* preds  = (const float*)d_in[0];
    const float* labels = (const float*)d_in[1];
    float* out = (float*)d_out;

    unsigned* counter = (unsigned*)d_ws;               // 4 B
    float* partial    = (float*)((char*)d_ws + 256);   // 676 floats

    // counter must be zero every call (ws poisoned 0xAA, not re-poisoned):
    hipMemsetAsync(counter, 0, sizeof(unsigned), stream);
    yolo_fused<<<kNBlk, kBlock, 0, stream>>>(preds, labels, out, partial, counter);
}

// Round 7
// 15.968 us; speedup vs baseline: 2.9268x; 2.9268x over previous
//
#include <hip/hip_runtime.h>

// YOLOv2 loss. preds [B,S,S,A,25] f32, labels [B,S,S,25] f32, out scalar f32.
// v7 = round-1 architecture (thread-per-cell, early-out, 2 kernels, no
// atomics/fences) + dwordx4 vectorization of all per-thread loads.
constexpr int kB     = 1024;
constexpr int kS     = 13;
constexpr int kA     = 5;
constexpr int kC5    = 25;
constexpr int kRec   = kA * kC5;          // 125
constexpr int kCells = kB * kS * kS;      // 173056
constexpr int kBlock = 256;
constexpr int kNBlk  = (kCells + kBlock - 1) / kBlock;  // 676 (exact)

using f4 = __attribute__((__ext_vector_type__(4))) float;

__device__ __forceinline__ f4 ld4(const float* __restrict__ p) {
    f4 r;
    __builtin_memcpy(&r, p, sizeof(r));   // dword-aligned dwordx4 on gfx950
    return r;
}

__global__ __launch_bounds__(kBlock)
void yolo_main(const float* __restrict__ preds,
               const float* __restrict__ labels,
               float* __restrict__ partial)
{
    const int tid  = threadIdx.x;
    const int lane = tid & 63;
    const int wid  = tid >> 6;
    const int cell = blockIdx.x * kBlock + tid;

    float loss = 0.0f;
    if (cell < kCells) {
        const float* __restrict__ lab = labels + (size_t)cell * kC5;
        const f4 g = ld4(lab + 1);                 // {ly, lw, lh, obj}
        if (g.w == 1.0f) {
            const float lx = lab[0], ly = g.x, lw = g.y, lh = g.z;
            const float lx1 = lx - lw * 0.5f, lx2 = lx + lw * 0.5f;
            const float ly1 = ly - lh * 0.5f, ly2 = ly + lh * 0.5f;
            const float larea = lw * lh;

            const float* __restrict__ p = preds + (size_t)cell * kRec;
            f4   box[kA];
            float iou[kA], conf[kA];
            int best = 0;
            float bestIou = -1.0f;
            #pragma unroll
            for (int a = 0; a < kA; ++a) {
                const float* pa = p + a * kC5;
                const f4 b = ld4(pa);              // {x, y, w, h} one dwordx4
                box[a]  = b;
                conf[a] = pa[4];
                const float px1 = b.x - b.z * 0.5f, px2 = b.x + b.z * 0.5f;
                const float py1 = b.y - b.w * 0.5f, py2 = b.y + b.w * 0.5f;
                const float iw = fmaxf(fminf(px2, lx2) - fmaxf(px1, lx1), 0.0f);
                const float ih = fmaxf(fminf(py2, ly2) - fmaxf(py1, ly1), 0.0f);
                const float inter = iw * ih;
                const float uni = b.z * b.w + larea - inter;
                const float v = inter / (uni + 1e-12f);
                iou[a] = v;
                if (v > bestIou) { bestIou = v; best = a; }  // strict > == jnp.argmax
            }

            const f4 bb = box[best];
            // xy
            const float dx = lx - bb.x, dy = ly - bb.y;
            loss += 5.0f * (dx * dx + dy * dy);
            // wh
            const float sw = sqrtf(lw) - sqrtf(bb.z);
            const float sh = sqrtf(lh) - sqrtf(bb.w);
            loss += sw * sw + sh * sh;
            // obj
            const float dob = bestIou - conf[best];
            loss += dob * dob;
            // cls: 20 floats each side = 5 dwordx4 each (4-B aligned)
            const float* __restrict__ bp = p + best * kC5;
            float cls = 0.0f;
            #pragma unroll
            for (int r = 0; r < 5; ++r) {
                const f4 lv = ld4(lab + 5 + 4 * r);
                const f4 pv = ld4(bp + 5 + 4 * r);
                const f4 d  = lv - pv;
                cls += d.x * d.x + d.y * d.y + d.z * d.z + d.w * d.w;
            }
            loss += cls;
            // noobj
            #pragma unroll
            for (int a = 0; a < kA; ++a) {
                if (a != best && iou[a] < 0.6f) {
                    const float d = iou[a] - conf[a];
                    loss += d * d;
                }
            }
        }
    }

    // block reduction: wave shuffle then LDS (no atomics, no fences)
    #pragma unroll
    for (int off = 32; off > 0; off >>= 1)
        loss += __shfl_down(loss, off, 64);
    __shared__ float sred[kBlock / 64];
    if (lane == 0) sred[wid] = loss;
    __syncthreads();
    if (tid == 0)
        partial[blockIdx.x] = sred[0] + sred[1] + sred[2] + sred[3];
}

__global__ __launch_bounds__(kBlock)
void yolo_reduce(const float* __restrict__ partial, float* __restrict__ out)
{
    float s = 0.0f;
    for (int i = threadIdx.x; i < kNBlk; i += kBlock)
        s += partial[i];
    #pragma unroll
    for (int off = 32; off > 0; off >>= 1)
        s += __shfl_down(s, off, 64);
    __shared__ float sred[kBlock / 64];
    const int lane = threadIdx.x & 63;
    const int wid  = threadIdx.x >> 6;
    if (lane == 0) sred[wid] = s;
    __syncthreads();
    if (threadIdx.x == 0) {
        float t = 0.0f;
        #pragma unroll
        for (int w = 0; w < kBlock / 64; ++w) t += sred[w];
        out[0] = t * (1.0f / (float)kB);
    }
}

extern "C" void kernel_launch(void* const* d_in, const int* in_sizes, int n_in,
                              void* d_out, int out_size, void* d_ws, size_t ws_size,
                              hipStream_t stream) {
    const float* preds  = (const float*)d_in[0];
    const float* labels = (const float*)d_in[1];
    float* out     = (float*)d_out;
    float* partial = (float*)d_ws;          // 676 floats; fully rewritten by K1 each call

    yolo_main<<<kNBlk, kBlock, 0, stream>>>(preds, labels, partial);
    yolo_reduce<<<1, kBlock, 0, stream>>>(partial, out);
}